// Round 9
// baseline (342.291 us; speedup 1.0000x reference)
//
#include <hip/hip_runtime.h>
#include <stdint.h>

// Problem: BS=8, N=2048, D=512
// out[b,i,d] = sigmoid(q)[b,i,d] * (eB @ (ek*v)) / (eB @ ek)
#define N_SEQ 2048
#define D_MODEL 512
#define MROWS 16384   // BS*N
#define NT_K 32       // K-tiles (K=2048 / BK=64) in main GEMM

typedef __attribute__((ext_vector_type(8))) short bf16x8;
typedef __attribute__((ext_vector_type(4))) float f32x4;

__device__ __forceinline__ short f2bf(float f) {
  union { float f; uint32_t u; } x; x.f = f;
  uint32_t r = x.u + 0x7FFFu + ((x.u >> 16) & 1u);
  return (short)(uint16_t)(r >> 16);
}
__device__ __forceinline__ unsigned short f2h(float f) {
  union { _Float16 h; unsigned short u; } x; x.h = (_Float16)f; return x.u;
}
__device__ __forceinline__ float h2f(unsigned short u) {
  union { unsigned short u; _Float16 h; } x; x.u = u; return (float)x.h;
}

__device__ __forceinline__ void gload_lds16(const void* g, void* l) {
  __builtin_amdgcn_global_load_lds(
      (__attribute__((address_space(1))) void*)(void*)g,
      (__attribute__((address_space(3))) void*)l, 16, 0, 0);
}

// ---------------- prep kernels ----------------

__global__ void k_conv_bf16(const float* __restrict__ in,
                            short* __restrict__ a, int n4) {
  int stride = gridDim.x * blockDim.x;
  for (int i = blockIdx.x * blockDim.x + threadIdx.x; i < n4; i += stride) {
    float4 v = reinterpret_cast<const float4*>(in)[i];
    short4 h;
    h.x = f2bf(v.x); h.y = f2bf(v.y); h.z = f2bf(v.z); h.w = f2bf(v.w);
    reinterpret_cast<short4*>(a)[i] = h;
  }
}

__global__ void k_prep_eb(const float* __restrict__ pb, short* __restrict__ eb,
                          int n4) {
  int stride = gridDim.x * blockDim.x;
  for (int i = blockIdx.x * blockDim.x + threadIdx.x; i < n4; i += stride) {
    float4 v = reinterpret_cast<const float4*>(pb)[i];
    short4 o;
    o.x = f2bf(expf(v.x));
    o.y = f2bf(expf(v.y));
    o.z = f2bf(expf(v.z));
    o.w = f2bf(expf(v.w));
    reinterpret_cast<short4*>(eb)[i] = o;
  }
}

// Wt[c][k] bf16, col-major over k.  c<512: Wq col c; c>=512: c=512+2d+s,
// s=0 -> Wk col d, s=1 -> Wv col d
__global__ void k_prep_w(const float* __restrict__ Wq, const float* __restrict__ Wk,
                         const float* __restrict__ Wv, short* __restrict__ wh) {
  int t = blockIdx.x * blockDim.x + threadIdx.x;
  if (t >= 1536 * 512) return;
  int c = t >> 9, k = t & 511;
  float v;
  if (c < 512) v = Wq[k * 512 + c];
  else {
    int cc = c - 512, d = cc >> 1;
    v = (cc & 1) ? Wv[k * 512 + d] : Wk[k * 512 + d];
  }
  wh[t] = f2bf(v);
}

// ---------------- projection GEMM (128^2 2-phase, unchanged) ----------------
// Epilogue writes X in MFMA-fragment-permuted layout Xf:
// element (col, j) lives at Xf[((ct*64 + kg)*64 + ln)*8 + (j&7)] where
// ct=col>>4, kg=j>>5, ln=(col&15) | (((j>>3)&3)<<4).  A wave's B-fragment
// (16 cols x 32 k) is then one contiguous 1 KB chunk: base + lane*16B.
__global__ __launch_bounds__(256) void k_proj(
    const short* __restrict__ A, const short* __restrict__ W,
    const float* __restrict__ bq, const float* __restrict__ bk,
    const float* __restrict__ bv,
    unsigned short* __restrict__ sigq, short* __restrict__ Xf) {
  __shared__ short lA[128 * 64], lB[128 * 64];
  const int tid = threadIdx.x;
  const int lane = tid & 63, wid = tid >> 6;
  const int wr = wid >> 1, wc = wid & 1;
  const int lrow = lane & 15;
  const int kq = (lane >> 4) << 4;
  const int row0 = blockIdx.x * 128;
  const int col0 = blockIdx.y * 128;

  const f32x4 fzero = {0.f, 0.f, 0.f, 0.f};
  f32x4 acc[4][4];
#pragma unroll
  for (int m = 0; m < 4; ++m)
#pragma unroll
    for (int n = 0; n < 4; ++n) acc[m][n] = fzero;

  const short* gA = A + row0 * 512;
  const short* gB = W + col0 * 512;

  for (int kt = 0; kt < 8; ++kt) {
    const int kb = kt * 64;
#pragma unroll
    for (int p = 0; p < 4; ++p) {
      int c = p * 256 + tid;
      int B = c << 4;
      int r = B >> 7;
      int wp = (B & 127) ^ ((r & 7) << 4);
      int ke = wp >> 1;
      int goff = r * 512 + kb + ke;
      int loff = (p * 256 + wid * 64) << 3;
      gload_lds16(gA + goff, lA + loff);
      gload_lds16(gB + goff, lB + loff);
    }
    __syncthreads();
#pragma unroll
    for (int ks = 0; ks < 2; ++ks) {
      int kb2 = kq + ks * 64;
      bf16x8 fb[4];
#pragma unroll
      for (int n = 0; n < 4; ++n) {
        int r = wc * 64 + n * 16 + lrow;
        fb[n] = *(const bf16x8*)((const char*)lB + (r << 7) +
                                 (kb2 ^ ((r & 7) << 4)));
      }
#pragma unroll
      for (int m = 0; m < 4; ++m) {
        int r = wr * 64 + m * 16 + lrow;
        bf16x8 fa = *(const bf16x8*)((const char*)lA + (r << 7) +
                                     (kb2 ^ ((r & 7) << 4)));
#pragma unroll
        for (int n = 0; n < 4; ++n)
          acc[m][n] = __builtin_amdgcn_mfma_f32_16x16x32_bf16(fa, fb[n], acc[m][n], 0, 0, 0);
      }
    }
    __syncthreads();
  }

  const int rbase = row0 + wr * 64 + ((lane >> 4) << 2);
  if (col0 < 512) {
#pragma unroll
    for (int n = 0; n < 4; ++n) {
      int c = col0 + wc * 64 + n * 16 + lrow;
      float bias = bq[c];
#pragma unroll
      for (int m = 0; m < 4; ++m) {
        int gr = rbase + m * 16;
#pragma unroll
        for (int r = 0; r < 4; ++r) {
          float q = acc[m][n][r] + bias;
          sigq[(gr + r) * 512 + c] = f2h(1.f / (1.f + expf(-q)));
        }
      }
    }
  } else {
    int s = lane & 1;
#pragma unroll
    for (int n = 0; n < 4; ++n) {
      int c = col0 + wc * 64 + n * 16 + lrow;
      int d = (c - 512) >> 1;
      float bias = s ? bv[d] : bk[d];
#pragma unroll
      for (int m = 0; m < 4; ++m) {
        int gr = rbase + m * 16;
        int b = gr >> 11;
        int j = gr & 2047;
        f32x4 val;
#pragma unroll
        for (int r = 0; r < 4; ++r) val[r] = acc[m][n][r] + bias;
        if (!s) {
#pragma unroll
          for (int r = 0; r < 4; ++r) val[r] = expf(val[r]);
        }
        f32x4 oth;
#pragma unroll
        for (int r = 0; r < 4; ++r) oth[r] = __shfl_xor(val[r], 1);
        if (!s) {
          short4 wq, eq;
          wq.x = f2bf(val[0] * oth[0]); eq.x = f2bf(val[0]);
          wq.y = f2bf(val[1] * oth[1]); eq.y = f2bf(val[1]);
          wq.z = f2bf(val[2] * oth[2]); eq.z = f2bf(val[2]);
          wq.w = f2bf(val[3] * oth[3]); eq.w = f2bf(val[3]);
          int colp = b * 1024 + 2 * d;  // num col; colp+1 = den col
          int kg = j >> 5;
          int sub = ((j >> 3) & 3) << 4;
          int e0 = j & 4;               // j % 8 is 0 or 4
          int ctn = colp >> 4;
          int lnn = (colp & 15) | sub;
          int lnd = ((colp + 1) & 15) | sub;
          *(short4*)&Xf[(((ctn * 64 + kg) * 64 + lnn) << 3) + e0] = wq;
          *(short4*)&Xf[(((ctn * 64 + kg) * 64 + lnd) << 3) + e0] = eq;
        }
      }
    }
  }
}

// ---------------- main GEMM v6: R8 structure + zero-VALU addressing ---------
// 256x128 tile, 512 thr = 8 waves (4M x 2N), 2 blocks/CU.
// A via LDS (2x32KB dbuf, XOR swizzle); B direct global->VGPR (frag layout),
// single fb[8] with WAR half-refill.  All addresses precomputed:
//   LDA: (vbase ^ (ks<<6)) + m*2048 + buf*32768   (imm-folded)
//   fb : SGPR uniform base (readfirstlane) + lane-const VGPR
//   STAGE: per-thread voffset + uniform t/p adds
// s_setprio(1) around MFMA clusters (T5; 2 blocks/CU give role diversity).

#define MFMA16(A_, B_, C_) __builtin_amdgcn_mfma_f32_16x16x32_bf16(A_, B_, C_, 0, 0, 0)

#define LDA6(BUF, KS, M)                                                     \
  (*(const bf16x8*)((const char*)lds + ((vbase ^ ((KS) << 6)) + (M) * 2048 + \
                                        ((BUF) << 15))))

#define LOADFB6(DST, T, KS)                                                  \
  {                                                                          \
    _Pragma("unroll") for (int n_ = 0; n_ < 4; ++n_) {                       \
      (DST)[n_] = *(const bf16x8*)(Xf + (((size_t)(ctu + n_)) << 15) +       \
                                   ((((T) * 2 + (KS))) << 9) + lvo);         \
    }                                                                        \
  }

#define MMH6(BUF, KS, FBH)                                                   \
  {                                                                          \
    bf16x8 fa0 = LDA6(BUF, KS, 0), fa1 = LDA6(BUF, KS, 1),                   \
           fa2 = LDA6(BUF, KS, 2), fa3 = LDA6(BUF, KS, 3);                   \
    __builtin_amdgcn_s_setprio(1);                                           \
    _Pragma("unroll") for (int n_ = 0; n_ < 4; ++n_) {                       \
      acc[0][n_] = MFMA16(fa0, (FBH)[n_], acc[0][n_]);                       \
      acc[1][n_] = MFMA16(fa1, (FBH)[n_], acc[1][n_]);                       \
      acc[2][n_] = MFMA16(fa2, (FBH)[n_], acc[2][n_]);                       \
      acc[3][n_] = MFMA16(fa3, (FBH)[n_], acc[3][n_]);                       \
    }                                                                        \
    __builtin_amdgcn_s_setprio(0);                                           \
  }

#define TILE6(T, BUF)                                                        \
  {                                                                          \
    if ((T) + 1 < NT_K) {                                                    \
      const int tk_ = ((T) + 1) << 6;                                        \
      gload_lds16(gA + svo0 + tk_, ldst0 + (((BUF) ^ 1) << 14));             \
      gload_lds16(gA + svo0 + 131072 + tk_, ldst1 + (((BUF) ^ 1) << 14));    \
      gload_lds16(gA + svo0 + 262144 + tk_, ldst2 + (((BUF) ^ 1) << 14));    \
      gload_lds16(gA + svo0 + 393216 + tk_, ldst3 + (((BUF) ^ 1) << 14));    \
    }                                                                        \
    MMH6(BUF, 0, fb);                                                        \
    if ((T) + 1 < NT_K) LOADFB6(fb, (T) + 1, 0);                             \
    MMH6(BUF, 1, fb + 4);                                                    \
    if ((T) + 1 < NT_K) LOADFB6(fb + 4, (T) + 1, 1);                         \
    __syncthreads();                                                         \
  }

__global__ __launch_bounds__(512, 4) void k_main6(
    const short* __restrict__ eB, const short* __restrict__ Xf,
    const unsigned short* __restrict__ sigq, float* __restrict__ out) {
  extern __shared__ short lds[];  // 32768 shorts = 64 KB (2 bufs)
  const int tid = threadIdx.x;
  const int lane = tid & 63, wid = tid >> 6;
  const int wr = wid >> 1, wc = wid & 1;  // 4M x 2N
  const int lrow = lane & 15;
  const int khi = (lane >> 4) << 4;

  // XCD chunk swizzle: 512 blocks = 8 Mtiles x 64 Ntiles; xcd (=bid%8) gets
  // all 8 rows x 8 cols.
  const int bid = blockIdx.x;
  const int xcd = bid & 7, bj = bid >> 3;
  const int row0 = (bj & 7) * 256;
  const int col0 = ((xcd << 3) + (bj >> 3)) * 128;

  const f32x4 fzero = {0.f, 0.f, 0.f, 0.f};
  f32x4 acc[4][4];
#pragma unroll
  for (int m = 0; m < 4; ++m)
#pragma unroll
    for (int n = 0; n < 4; ++n) acc[m][n] = fzero;

  const short* gA = eB + row0 * 2048;

  // --- precomputed addressing ---
  // LDS A-read base (bytes): R = wr*64 + lrow rows, swizzled k part
  const int sw = (lrow & 7) << 4;
  const int vbase = (wr * 64 + lrow) * 128 + (khi ^ sw);
  // STAGE: per-thread global voffset (shorts); p-stride 131072, t-stride 64
  const int svo0 = ((tid >> 3) * 2048) +
                   (((((tid & 7) << 4) ^ (((tid >> 3) & 7) << 4))) >> 1);
  // STAGE LDS dests (wave-uniform + lane*16 implicit), shorts
  short* ldst0 = lds + (wid << 9);
  short* ldst1 = lds + 4096 + (wid << 9);
  short* ldst2 = lds + 8192 + (wid << 9);
  short* ldst3 = lds + 12288 + (wid << 9);
  // fb: uniform frag base (SGPR via readfirstlane) + lane-const VGPR
  const int ctu = __builtin_amdgcn_readfirstlane((col0 >> 4) + wc * 4);
  const int lvo = lane << 3;  // lane*8 shorts = 16B

  bf16x8 fb[8];

  // prologue: A tile0 -> buf0, B tile0 -> fb
  gload_lds16(gA + svo0, ldst0);
  gload_lds16(gA + svo0 + 131072, ldst1);
  gload_lds16(gA + svo0 + 262144, ldst2);
  gload_lds16(gA + svo0 + 393216, ldst3);
  LOADFB6(fb, 0, 0);
  LOADFB6(fb + 4, 0, 1);
  __syncthreads();

  for (int t = 0; t < NT_K; t += 2) {
    TILE6(t, 0);
    TILE6(t + 1, 1);
  }

  // epilogue: C/D frag col = lane&15, row = (lane>>4)*4 + reg
  const int rbase = row0 + wr * 64 + ((lane >> 4) << 2);
#pragma unroll
  for (int n = 0; n < 4; ++n) {
    int c = col0 + wc * 64 + n * 16 + lrow;
    int b = c >> 10;
    int d = (c & 1023) >> 1;
#pragma unroll
    for (int m = 0; m < 4; ++m) {
      f32x4 den;
#pragma unroll
      for (int r = 0; r < 4; ++r) den[r] = __shfl_xor(acc[m][n][r], 1);
      if ((lane & 1) == 0) {  // even lane: acc=num, partner holds den
#pragma unroll
        for (int r = 0; r < 4; ++r) {
          int i2 = rbase + m * 16 + r;
          int idx = (b * 2048 + i2) * 512 + d;
          out[idx] = h2f(sigq[idx]) * (acc[m][n][r] / den[r]);
        }
      }
    }
  }
}

// ---------------- launch ----------------
extern "C" void kernel_launch(void* const* d_in, const int* in_sizes, int n_in,
                              void* d_out, int out_size, void* d_ws, size_t ws_size,
                              hipStream_t stream) {
  const float* in = (const float*)d_in[0];
  const float* Wq = (const float*)d_in[1];
  const float* bq = (const float*)d_in[2];
  const float* Wk = (const float*)d_in[3];
  const float* bk = (const float*)d_in[4];
  const float* Wv = (const float*)d_in[5];
  const float* bv = (const float*)d_in[6];
  const float* pb = (const float*)d_in[7];
  float* out = (float*)d_out;

  char* ws = (char*)d_ws;
  short* Xf = (short*)ws;                              // 33,554,432 B
  short* eB = (short*)(ws + 33554432);                 //  8,388,608 B
  short* Ah = (short*)(ws + 41943040);                 // 16,777,216 B
  short* Wh = (short*)(ws + 58720256);                 //  1,572,864 B
  unsigned short* sigq = (unsigned short*)(ws + 60293120);  // 16,777,216 B

  (void)hipFuncSetAttribute((const void*)k_main6,
                            hipFuncAttributeMaxDynamicSharedMemorySize, 65536);

  k_conv_bf16<<<2048, 256, 0, stream>>>(in, Ah, MROWS * D_MODEL / 4);
  k_prep_w<<<3072, 256, 0, stream>>>(Wq, Wk, Wv, Wh);
  k_prep_eb<<<2048, 256, 0, stream>>>(pb, eB, N_SEQ * N_SEQ / 4);

  dim3 gp(128, 12);
  k_proj<<<gp, 256, 0, stream>>>(Ah, Wh, bq, bk, bv, sigq, Xf);

  k_main6<<<dim3(512), 512, 65536, stream>>>(eB, Xf, sigq, out);
}

// Round 10
// 149.083 us; speedup vs baseline: 2.2960x; 2.2960x over previous
//
#include <hip/hip_runtime.h>
#include <stdint.h>

// Problem: BS=8, N=2048, D=512
// out[b,i,d] = sigmoid(q)[b,i,d] * (eB @ (ek*v)) / (eB @ ek)
#define N_SEQ 2048
#define D_MODEL 512
#define MROWS 16384   // BS*N
#define NT_K 32       // K-tiles (K=2048 / BK=64) in main GEMM

typedef __attribute__((ext_vector_type(8))) short bf16x8;
typedef __attribute__((ext_vector_type(4))) float f32x4;

__device__ __forceinline__ short f2bf(float f) {
  union { float f; uint32_t u; } x; x.f = f;
  uint32_t r = x.u + 0x7FFFu + ((x.u >> 16) & 1u);
  return (short)(uint16_t)(r >> 16);
}
__device__ __forceinline__ unsigned short f2h(float f) {
  union { _Float16 h; unsigned short u; } x; x.h = (_Float16)f; return x.u;
}
__device__ __forceinline__ float h2f(unsigned short u) {
  union { unsigned short u; _Float16 h; } x; x.u = u; return (float)x.h;
}

__device__ __forceinline__ void gload_lds16(const void* g, void* l) {
  __builtin_amdgcn_global_load_lds(
      (__attribute__((address_space(1))) void*)(void*)g,
      (__attribute__((address_space(3))) void*)l, 16, 0, 0);
}

// ---------------- prep kernels ----------------

__global__ void k_conv_bf16(const float* __restrict__ in,
                            short* __restrict__ a, int n4) {
  int stride = gridDim.x * blockDim.x;
  for (int i = blockIdx.x * blockDim.x + threadIdx.x; i < n4; i += stride) {
    float4 v = reinterpret_cast<const float4*>(in)[i];
    short4 h;
    h.x = f2bf(v.x); h.y = f2bf(v.y); h.z = f2bf(v.z); h.w = f2bf(v.w);
    reinterpret_cast<short4*>(a)[i] = h;
  }
}

__global__ void k_prep_eb(const float* __restrict__ pb, short* __restrict__ eb,
                          int n4) {
  int stride = gridDim.x * blockDim.x;
  for (int i = blockIdx.x * blockDim.x + threadIdx.x; i < n4; i += stride) {
    float4 v = reinterpret_cast<const float4*>(pb)[i];
    short4 o;
    o.x = f2bf(expf(v.x));
    o.y = f2bf(expf(v.y));
    o.z = f2bf(expf(v.z));
    o.w = f2bf(expf(v.w));
    reinterpret_cast<short4*>(eb)[i] = o;
  }
}

// Wt[c][k] bf16, col-major over k.  c<512: Wq col c; c>=512: c=512+2d+s,
// s=0 -> Wk col d, s=1 -> Wv col d
__global__ void k_prep_w(const float* __restrict__ Wq, const float* __restrict__ Wk,
                         const float* __restrict__ Wv, short* __restrict__ wh) {
  int t = blockIdx.x * blockDim.x + threadIdx.x;
  if (t >= 1536 * 512) return;
  int c = t >> 9, k = t & 511;
  float v;
  if (c < 512) v = Wq[k * 512 + c];
  else {
    int cc = c - 512, d = cc >> 1;
    v = (cc & 1) ? Wv[k * 512 + d] : Wk[k * 512 + d];
  }
  wh[t] = f2bf(v);
}

// ---------------- projection GEMM (128^2 2-phase) ----------------
// Epilogue writes X in kg-major MFMA-fragment layout Xf:
// element (col, j) lives at Xf[(kg*512 + ct)*512 + ln*8 + (j&7)] where
// ct=col>>4, kg=j>>5, ln=(col&15) | (((j>>3)&3)<<4).  A wave's 4 B-frags for
// one (kt,ks) are then at base + kg*2^18 + ct*512 + lane*8 + n*512 — the
// n*512 folds into the load immediate, kg*2^18 is one uniform add per half.
__global__ __launch_bounds__(256) void k_proj(
    const short* __restrict__ A, const short* __restrict__ W,
    const float* __restrict__ bq, const float* __restrict__ bk,
    const float* __restrict__ bv,
    unsigned short* __restrict__ sigq, short* __restrict__ Xf) {
  __shared__ short lA[128 * 64], lB[128 * 64];
  const int tid = threadIdx.x;
  const int lane = tid & 63, wid = tid >> 6;
  const int wr = wid >> 1, wc = wid & 1;
  const int lrow = lane & 15;
  const int kq = (lane >> 4) << 4;
  const int row0 = blockIdx.x * 128;
  const int col0 = blockIdx.y * 128;

  const f32x4 fzero = {0.f, 0.f, 0.f, 0.f};
  f32x4 acc[4][4];
#pragma unroll
  for (int m = 0; m < 4; ++m)
#pragma unroll
    for (int n = 0; n < 4; ++n) acc[m][n] = fzero;

  const short* gA = A + row0 * 512;
  const short* gB = W + col0 * 512;

  for (int kt = 0; kt < 8; ++kt) {
    const int kb = kt * 64;
#pragma unroll
    for (int p = 0; p < 4; ++p) {
      int c = p * 256 + tid;
      int B = c << 4;
      int r = B >> 7;
      int wp = (B & 127) ^ ((r & 7) << 4);
      int ke = wp >> 1;
      int goff = r * 512 + kb + ke;
      int loff = (p * 256 + wid * 64) << 3;
      gload_lds16(gA + goff, lA + loff);
      gload_lds16(gB + goff, lB + loff);
    }
    __syncthreads();
#pragma unroll
    for (int ks = 0; ks < 2; ++ks) {
      int kb2 = kq + ks * 64;
      bf16x8 fb[4];
#pragma unroll
      for (int n = 0; n < 4; ++n) {
        int r = wc * 64 + n * 16 + lrow;
        fb[n] = *(const bf16x8*)((const char*)lB + (r << 7) +
                                 (kb2 ^ ((r & 7) << 4)));
      }
#pragma unroll
      for (int m = 0; m < 4; ++m) {
        int r = wr * 64 + m * 16 + lrow;
        bf16x8 fa = *(const bf16x8*)((const char*)lA + (r << 7) +
                                     (kb2 ^ ((r & 7) << 4)));
#pragma unroll
        for (int n = 0; n < 4; ++n)
          acc[m][n] = __builtin_amdgcn_mfma_f32_16x16x32_bf16(fa, fb[n], acc[m][n], 0, 0, 0);
      }
    }
    __syncthreads();
  }

  const int rbase = row0 + wr * 64 + ((lane >> 4) << 2);
  if (col0 < 512) {
#pragma unroll
    for (int n = 0; n < 4; ++n) {
      int c = col0 + wc * 64 + n * 16 + lrow;
      float bias = bq[c];
#pragma unroll
      for (int m = 0; m < 4; ++m) {
        int gr = rbase + m * 16;
#pragma unroll
        for (int r = 0; r < 4; ++r) {
          float q = acc[m][n][r] + bias;
          sigq[(gr + r) * 512 + c] = f2h(1.f / (1.f + expf(-q)));
        }
      }
    }
  } else {
    int s = lane & 1;
#pragma unroll
    for (int n = 0; n < 4; ++n) {
      int c = col0 + wc * 64 + n * 16 + lrow;
      int d = (c - 512) >> 1;
      float bias = s ? bv[d] : bk[d];
#pragma unroll
      for (int m = 0; m < 4; ++m) {
        int gr = rbase + m * 16;
        int b = gr >> 11;
        int j = gr & 2047;
        f32x4 val;
#pragma unroll
        for (int r = 0; r < 4; ++r) val[r] = acc[m][n][r] + bias;
        if (!s) {
#pragma unroll
          for (int r = 0; r < 4; ++r) val[r] = expf(val[r]);
        }
        f32x4 oth;
#pragma unroll
        for (int r = 0; r < 4; ++r) oth[r] = __shfl_xor(val[r], 1);
        if (!s) {
          short4 wq, eq;
          wq.x = f2bf(val[0] * oth[0]); eq.x = f2bf(val[0]);
          wq.y = f2bf(val[1] * oth[1]); eq.y = f2bf(val[1]);
          wq.z = f2bf(val[2] * oth[2]); eq.z = f2bf(val[2]);
          wq.w = f2bf(val[3] * oth[3]); eq.w = f2bf(val[3]);
          int colp = b * 1024 + 2 * d;  // num col; colp+1 = den col
          int kg = j >> 5;
          int sub = ((j >> 3) & 3) << 4;
          int e0 = j & 4;               // j % 8 is 0 or 4
          int ctn = colp >> 4;
          int lnn = (colp & 15) | sub;
          int lnd = ((colp + 1) & 15) | sub;
          // kg-major: Xf[(kg<<18) + ct*512 + ln*8 + e0]
          *(short4*)&Xf[(kg << 18) + (ctn << 9) + (lnn << 3) + e0] = wq;
          *(short4*)&Xf[(kg << 18) + (ctn << 9) + (lnd << 3) + e0] = eq;
        }
      }
    }
  }
}

// ---------------- main GEMM v7: R8 structure + kg-major B layout -----------
// 256x128 tile, 512 thr = 8 waves (4M x 2N), 2 blocks/CU.
// A via LDS (2x32KB dbuf, XOR swizzle); B direct global->VGPR from kg-major
// Xf: one per-thread offset VGPR (pfo), kg*2^18 uniform add CSE'd per half,
// n*512 in the load immediate.  Single fb[8] with WAR half-refill.
// s_setprio around MFMA clusters (2 blocks/CU give scheduler role diversity).
__global__ __launch_bounds__(512, 4) void k_main7(
    const short* __restrict__ eB, const short* __restrict__ Xf,
    const unsigned short* __restrict__ sigq, float* __restrict__ out) {
  extern __shared__ short lds[];  // 32768 shorts = 64 KB (2 bufs)
  const int tid = threadIdx.x;
  const int lane = tid & 63, wid = tid >> 6;
  const int wr = wid >> 1, wc = wid & 1;  // 4M x 2N
  const int lrow = lane & 15;
  const int khi = (lane >> 4) << 4;  // lane's k-byte suboffset within 64B

  // XCD chunk swizzle: 512 blocks = 8 Mtiles x 64 Ntiles; xcd (=bid%8) gets
  // all 8 rows x 8 cols.
  const int bid = blockIdx.x;
  const int xcd = bid & 7, bj = bid >> 3;
  const int row0 = (bj & 7) * 256;
  const int col0 = ((xcd << 3) + (bj >> 3)) * 128;

  const f32x4 fzero = {0.f, 0.f, 0.f, 0.f};
  f32x4 acc[4][4];
#pragma unroll
  for (int m = 0; m < 4; ++m)
#pragma unroll
    for (int n = 0; n < 4; ++n) acc[m][n] = fzero;

  const short* gA = eB + row0 * 2048;
  // per-thread B offset (shorts): ct*512 + lane*8, ct = col0/16 + wc*4
  const int pfo = (col0 << 5) + (wc << 11) + (lane << 3);

  // stage A-tile kt (256 rows x 64 k = 32 KB) into buf kt&1: 4 chunks/thread
  auto STAGE = [&](int kt) {
    const short* src = gA + kt * 64;
    const int sb = (kt & 1) << 14;  // buf base in shorts
#pragma unroll
    for (int p = 0; p < 4; ++p) {
      int c = p * 512 + tid;
      int r = c >> 3;
      int ke = ((((c & 7) << 4) ^ ((r & 7) << 4)) >> 1);
      gload_lds16(src + r * 2048 + ke,
                  lds + sb + ((p * 512 + wid * 64) << 3));
    }
  };
  auto LDA = [&](int b, int ks, int m) -> bf16x8 {
    int R = wr * 64 + m * 16 + lrow;
    int kb = ks * 64 + khi;
    return *(const bf16x8*)((const char*)lds + (b << 15) + R * 128 +
                            (kb ^ ((R & 7) << 4)));
  };
  // load 4 B-fragments (ks half of K-tile kt) into fb[0..3]; kg = kt*2+ks
  auto LOADFB = [&](bf16x8* fb, int kt, int ks) {
    const short* base = Xf + (((size_t)(kt * 2 + ks)) << 18) + pfo;
#pragma unroll
    for (int n = 0; n < 4; ++n)
      fb[n] = *(const bf16x8*)(base + (n << 9));
  };

  bf16x8 fb[8];

  // prologue: A tile0 -> buf0, B tile0 -> fb
  STAGE(0);
  LOADFB(fb, 0, 0);
  LOADFB(fb + 4, 0, 1);
  __syncthreads();  // full drain: buf0 + fb ready

  for (int t = 0; t < NT_K; ++t) {
    const int b = t & 1;
    if (t + 1 < NT_K) STAGE(t + 1);
    // ks0: MFMA with fb[0..3], then refill them for tile t+1
    {
      bf16x8 fa[4];
#pragma unroll
      for (int m = 0; m < 4; ++m) fa[m] = LDA(b, 0, m);
      __builtin_amdgcn_s_setprio(1);
#pragma unroll
      for (int m = 0; m < 4; ++m)
#pragma unroll
        for (int n = 0; n < 4; ++n)
          acc[m][n] = __builtin_amdgcn_mfma_f32_16x16x32_bf16(
              fa[m], fb[n], acc[m][n], 0, 0, 0);
      __builtin_amdgcn_s_setprio(0);
    }
    if (t + 1 < NT_K) LOADFB(fb, t + 1, 0);
    // ks1: MFMA with fb[4..7], then refill them for tile t+1
    {
      bf16x8 fa[4];
#pragma unroll
      for (int m = 0; m < 4; ++m) fa[m] = LDA(b, 1, m);
      __builtin_amdgcn_s_setprio(1);
#pragma unroll
      for (int m = 0; m < 4; ++m)
#pragma unroll
        for (int n = 0; n < 4; ++n)
          acc[m][n] = __builtin_amdgcn_mfma_f32_16x16x32_bf16(
              fa[m], fb[4 + n], acc[m][n], 0, 0, 0);
      __builtin_amdgcn_s_setprio(0);
    }
    if (t + 1 < NT_K) LOADFB(fb + 4, t + 1, 1);
    __syncthreads();  // drains STAGE+LOADFB (covered by ks-MFMAs); swap bufs
  }

  // epilogue: C/D frag col = lane&15, row = (lane>>4)*4 + reg
  const int rbase = row0 + wr * 64 + ((lane >> 4) << 2);
#pragma unroll
  for (int n = 0; n < 4; ++n) {
    int c = col0 + wc * 64 + n * 16 + lrow;
    int b = c >> 10;
    int d = (c & 1023) >> 1;
#pragma unroll
    for (int m = 0; m < 4; ++m) {
      f32x4 den;
#pragma unroll
      for (int r = 0; r < 4; ++r) den[r] = __shfl_xor(acc[m][n][r], 1);
      if ((lane & 1) == 0) {  // even lane: acc=num, partner holds den
#pragma unroll
        for (int r = 0; r < 4; ++r) {
          int i2 = rbase + m * 16 + r;
          int idx = (b * 2048 + i2) * 512 + d;
          out[idx] = h2f(sigq[idx]) * (acc[m][n][r] / den[r]);
        }
      }
    }
  }
}

// ---------------- launch ----------------
extern "C" void kernel_launch(void* const* d_in, const int* in_sizes, int n_in,
                              void* d_out, int out_size, void* d_ws, size_t ws_size,
                              hipStream_t stream) {
  const float* in = (const float*)d_in[0];
  const float* Wq = (const float*)d_in[1];
  const float* bq = (const float*)d_in[2];
  const float* Wk = (const float*)d_in[3];
  const float* bk = (const float*)d_in[4];
  const float* Wv = (const float*)d_in[5];
  const float* bv = (const float*)d_in[6];
  const float* pb = (const float*)d_in[7];
  float* out = (float*)d_out;

  char* ws = (char*)d_ws;
  short* Xf = (short*)ws;                              // 33,554,432 B
  short* eB = (short*)(ws + 33554432);                 //  8,388,608 B
  short* Ah = (short*)(ws + 41943040);                 // 16,777,216 B
  short* Wh = (short*)(ws + 58720256);                 //  1,572,864 B
  unsigned short* sigq = (unsigned short*)(ws + 60293120);  // 16,777,216 B

  (void)hipFuncSetAttribute((const void*)k_main7,
                            hipFuncAttributeMaxDynamicSharedMemorySize, 65536);

  k_conv_bf16<<<2048, 256, 0, stream>>>(in, Ah, MROWS * D_MODEL / 4);
  k_prep_w<<<3072, 256, 0, stream>>>(Wq, Wk, Wv, Wh);
  k_prep_eb<<<2048, 256, 0, stream>>>(pb, eB, N_SEQ * N_SEQ / 4);

  dim3 gp(128, 12);
  k_proj<<<gp, 256, 0, stream>>>(Ah, Wh, bq, bk, bv, sigq, Xf);

  k_main7<<<dim3(512), 512, 65536, stream>>>(eB, Xf, sigq, out);
}